// Round 13
// baseline (12924.982 us; speedup 1.0000x reference)
//
#include <hip/hip_runtime.h>
#include <math.h>

#define BATCH 32
#define TLEN  512
#define HID   1024
#define G2    2048   // 2*H
#define BHID (BATCH * HID)

typedef _Float16 half8 __attribute__((ext_vector_type(8)));
typedef _Float16 half2v __attribute__((ext_vector_type(2)));
typedef float f32x4 __attribute__((ext_vector_type(4)));

// ---------------------------------------------------------------------------
// fp32 -> fp16 conversion (8 elems/thread)
// ---------------------------------------------------------------------------
__global__ __launch_bounds__(256)
void conv_f16(const float* __restrict__ s, _Float16* __restrict__ d, int n8) {
    int i = blockIdx.x * 256 + threadIdx.x;
    if (i < n8) {
        int base = i * 8;
        float4 v0 = *(const float4*)&s[base];
        float4 v1 = *(const float4*)&s[base + 4];
        half8 h;
        h[0] = (_Float16)v0.x; h[1] = (_Float16)v0.y;
        h[2] = (_Float16)v0.z; h[3] = (_Float16)v0.w;
        h[4] = (_Float16)v1.x; h[5] = (_Float16)v1.y;
        h[6] = (_Float16)v1.z; h[7] = (_Float16)v1.w;
        *(half8*)&d[base] = h;
    }
}

// ---------------------------------------------------------------------------
// MFMA projection GEMM (proven R11/R12): Cw[t][b][n] = sum_k A[m][k]*W[n][k],
// m = b*T + t. Output now fp16.
// ---------------------------------------------------------------------------
__global__ __launch_bounds__(256)
void proj_gemm_f16(const _Float16* __restrict__ A, const _Float16* __restrict__ W,
                   _Float16* __restrict__ Cw, int K) {
    const int tid = threadIdx.x;
    const int wv = tid >> 6;
    const int l  = tid & 63;
    const int m0 = blockIdx.x * 128 + (wv >> 1) * 64;
    const int n0 = blockIdx.y * 128 + (wv & 1) * 64;
    const int fr = l & 15;
    const int kg = l >> 4;

    f32x4 acc[4][4];
    #pragma unroll
    for (int i = 0; i < 4; ++i)
        #pragma unroll
        for (int j = 0; j < 4; ++j) acc[i][j] = (f32x4){0.f, 0.f, 0.f, 0.f};

    const int nkc = K >> 5;
    #pragma unroll 2
    for (int kc = 0; kc < nkc; ++kc) {
        int k = kc * 32 + kg * 8;
        half8 af[4], bf[4];
        #pragma unroll
        for (int i = 0; i < 4; ++i)
            af[i] = *(const half8*)&A[(size_t)(m0 + i * 16 + fr) * K + k];
        #pragma unroll
        for (int j = 0; j < 4; ++j)
            bf[j] = *(const half8*)&W[(size_t)(n0 + j * 16 + fr) * K + k];
        #pragma unroll
        for (int i = 0; i < 4; ++i)
            #pragma unroll
            for (int j = 0; j < 4; ++j)
                acc[i][j] = __builtin_amdgcn_mfma_f32_16x16x32_f16(
                    af[i], bf[j], acc[i][j], 0, 0, 0);
    }

    // C layout: col = l&15, row = (l>>4)*4 + r
    #pragma unroll
    for (int i = 0; i < 4; ++i) {
        #pragma unroll
        for (int r = 0; r < 4; ++r) {
            int m = m0 + i * 16 + (l >> 4) * 4 + r;
            int t = m & (TLEN - 1);
            int b = m >> 9;
            _Float16* dst = &Cw[((size_t)t * BATCH + b) * G2];
            #pragma unroll
            for (int j = 0; j < 4; ++j)
                dst[n0 + j * 16 + (l & 15)] = (_Float16)acc[i][j][r];
        }
    }
}

// ---------------------------------------------------------------------------
// Agent-scope (device-coherent) helpers: sc0 sc1, bypass L1/per-XCD L2.
// ---------------------------------------------------------------------------
__device__ __forceinline__ void st_flag(int* p, int v) {
    __hip_atomic_store(p, v, __ATOMIC_RELAXED, __HIP_MEMORY_SCOPE_AGENT);
}
__device__ __forceinline__ int ld_flag(const int* p) {
    return __hip_atomic_load(p, __ATOMIC_RELAXED, __HIP_MEMORY_SCOPE_AGENT);
}
__device__ __forceinline__ unsigned long long ld_h2u(const unsigned short* p) {
    return __hip_atomic_load((const unsigned long long*)p, __ATOMIC_RELAXED,
                             __HIP_MEMORY_SCOPE_AGENT);
}
__device__ __forceinline__ void st_h32(unsigned int* p, unsigned int v) {
    __hip_atomic_store(p, v, __ATOMIC_RELAXED, __HIP_MEMORY_SCOPE_AGENT);
}

#define NWGR 32      // rec workgroups
#define FSTRIDE 16   // flags 64 B apart (256 wave-flags)

__global__ void rec_init(unsigned short* h0, int* flags) {
    int i = blockIdx.x * 256 + threadIdx.x;
    if (i < BHID) h0[i] = 0;              // fp16 +0.0
    if (i < NWGR * 8 * FSTRIDE) flags[i] = 0;
}

// ---------------------------------------------------------------------------
// MFMA recurrence, no-K-split version.
// 32 WGs x 512 thr (8 waves). wg: bt = wg&1 (2 batch-groups x 16 batches),
// jg = wg>>1 (0..15), j0 = jg*64. WG owns 64 j x 16 batches.
//
// Wave wv owns a 16-row M-tile covering FULL K=1024 (32 chained MFMAs, two
// interleaved acc chains) -- no cross-wave reduce, no partials LDS.
// M-tile rows INTERLEAVE a/z: row r16 -> j = j0+wv*8+(r16>>1), type r16&1
// (a/z). C-frag acc = (a_j, z_j, a_j+1, z_j+1) per lane -> gates fully
// in-lane, computed by ALL 512 threads (2 outputs each).
// A (U fp16) STREAMS from L2 (256 KB/WG/step, slice stays L2-hot) -- no
// register residency, no VGPR wall.
// B: h(t) staged once into XOR-swizzled LDS (2 x 32 KB double buffer), so
// ONE __syncthreads per step. Publish per-wave: vmcnt(0) + own wave-flag.
// Cross-WG sync: 3-ring + poll of the group's 128 wave-flags (2/lane).
// ---------------------------------------------------------------------------
__global__ __launch_bounds__(512, 1)
void ligru_rec(const _Float16* __restrict__ w16,   // [T][B][2H] fp16
               const _Float16* __restrict__ U16,   // [2H][H] fp16
               unsigned short* __restrict__ hring, // [3][B][H] fp16 ring
               int* __restrict__ flags,            // 256 wave-flags
               float* __restrict__ out32,          // [B][T][H] fp32 (layer 1)
               _Float16* __restrict__ act16,       // [B][T][H] fp16 (layer 0)
               float* __restrict__ hlast) {        // [B][H] fp32
    __shared__ char hsh[2][16 * 2048];             // 64 KB, XOR-swizzled

    const int wg  = blockIdx.x;       // 0..31
    const int tid = threadIdx.x;
    const int bt  = wg & 1;
    const int jg  = wg >> 1;          // 0..15
    const int j0  = jg * 64;
    const int bg0 = bt * 16;

    const int wv  = tid >> 6;         // wave 0..7 = M-tile
    const int l   = tid & 63;
    const int r16 = l & 15;           // A row / B col within tile
    const int kg  = l >> 4;           // k-group (8 halves)

    // A row: interleaved a/z pairs
    const int urow = ((r16 & 1) ? HID : 0) + j0 + wv * 8 + (r16 >> 1);
    const _Float16* Abase = U16 + (size_t)urow * HID;

    const int bcol  = bg0 + r16;                  // gate/C batch
    const int jbase = j0 + wv * 8 + (l >> 4) * 2; // gate j-pair (even)
    const int swz   = (r16 & 7) << 4;             // LDS XOR swizzle for B col

    // poll ids: group = 16 WGs (same bt) x 8 waves = 128 flags, 2 per lane
    const int* fpA = &flags[((2 * (l >> 3) + bt) * 8 + (l & 7)) * FSTRIDE];
    const int* fpB = &flags[((2 * ((l >> 3) + 8) + bt) * 8 + (l & 7)) * FSTRIDE];
    int* myflag = &flags[(wg * 8 + wv) * FSTRIDE];

    unsigned short* h_t = hring;
    unsigned short* h_n = hring + BHID;
    unsigned short* h_p = hring + 2 * BHID;

    float hp0 = 0.f, hp1 = 0.f;       // private h state (2 outputs/lane)

    for (int t = 0; t < TLEN; ++t) {
        // ---- w prefetch (plain cached fp16; issued before poll)
        const _Float16* wt = &w16[((size_t)t * BATCH + bcol) * G2];
        half2v wa = *(const half2v*)&wt[jbase];
        half2v wz = *(const half2v*)&wt[HID + jbase];

        // ---- poll the group's 128 wave-flags (2 per lane)
        if (t > 0) {
            while (ld_flag(fpA) < t || ld_flag(fpB) < t)
                __builtin_amdgcn_s_sleep(1);
        }

        // ---- stage h(t) -> LDS buf[t&1] (coherent 8B loads, XOR swizzle)
        {
            char* dst = hsh[t & 1];
            const unsigned short* src = h_t + (size_t)bg0 * HID;
            #pragma unroll
            for (int c = 0; c < 8; ++c) {
                int f  = tid * 8 + c;          // 0..4095 8B-blocks
                int b  = f >> 8;               // local batch 0..15
                int k8 = f & 255;              // 8B block within batch
                unsigned long long v = ld_h2u(src + (size_t)b * HID + k8 * 4);
                *(unsigned long long*)(dst + b * 2048 +
                                       ((k8 * 8) ^ ((b & 7) << 4))) = v;
            }
        }
        __syncthreads();   // the ONLY block barrier per step

        // ---- MFMA: 32 k-chunks, full K, 2 interleaved acc chains
        f32x4 acc0 = {0.f, 0.f, 0.f, 0.f};
        f32x4 acc1 = {0.f, 0.f, 0.f, 0.f};
        {
            const char* bsrc = hsh[t & 1] + r16 * 2048;
            #pragma unroll 8
            for (int kc = 0; kc < 32; ++kc) {
                half8 Af = *(const half8*)(Abase + kc * 32 + kg * 8);
                half8 Bf = *(const half8*)(bsrc + ((kc * 64 + kg * 16) ^ swz));
                if (kc & 1)
                    acc1 = __builtin_amdgcn_mfma_f32_16x16x32_f16(Af, Bf, acc1, 0, 0, 0);
                else
                    acc0 = __builtin_amdgcn_mfma_f32_16x16x32_f16(Af, Bf, acc0, 0, 0, 0);
            }
        }
        f32x4 s = acc0 + acc1;   // (a_j, z_j, a_j1, z_j1) for batch bcol

        // ---- gates, fully in-lane (all 512 threads, 2 outputs each)
        float at0 = (float)wa[0] + s[0];
        float zt0 = (float)wz[0] + s[1];
        float at1 = (float)wa[1] + s[2];
        float zt1 = (float)wz[1] + s[3];
        zt0 = 1.f / (1.f + expf(-zt0));
        zt1 = 1.f / (1.f + expf(-zt1));
        float hc0 = tanhf(at0), hc1 = tanhf(at1);
        float hn0 = zt0 * hp0 + (1.f - zt0) * hc0;
        float hn1 = zt1 * hp1 + (1.f - zt1) * hc1;
        hp0 = hn0; hp1 = hn1;

        size_t oidx = ((size_t)bcol * TLEN + t) * HID + jbase;
        unsigned short u0 = __builtin_bit_cast(unsigned short, (_Float16)hn0);
        unsigned short u1 = __builtin_bit_cast(unsigned short, (_Float16)hn1);
        unsigned int pk = (unsigned int)u0 | ((unsigned int)u1 << 16);
        if (act16) {
            *(unsigned int*)&act16[oidx] = pk;
        } else {
            *(float2*)&out32[oidx] = make_float2(hn0, hn1);
        }

        // ---- publish (per-wave: drain own stores, post own flag)
        if (t < TLEN - 1) {
            st_h32((unsigned int*)&h_n[(size_t)bcol * HID + jbase], pk);
            asm volatile("s_waitcnt vmcnt(0)" ::: "memory");
            if (l == 0) st_flag(myflag, t + 1);
        } else {
            *(float2*)&hlast[(size_t)bcol * HID + jbase] = make_float2(hn0, hn1);
        }

        unsigned short* tmp = h_t; h_t = h_n; h_n = h_p; h_p = tmp;
    }
}

// ---------------------------------------------------------------------------
extern "C" void kernel_launch(void* const* d_in, const int* in_sizes, int n_in,
                              void* d_out, int out_size, void* d_ws, size_t ws_size,
                              hipStream_t stream) {
    (void)in_sizes; (void)n_in; (void)out_size; (void)ws_size;

    const float* x  = (const float*)d_in[0];
    const float* W0 = (const float*)d_in[1];
    const float* U0 = (const float*)d_in[2];
    const float* W1 = (const float*)d_in[3];
    const float* U1 = (const float*)d_in[4];

    float* out    = (float*)d_out;                              // [B,T,H]
    float* hstack = out + (size_t)BATCH * TLEN * HID;           // [2,B,H]

    // workspace layout (~104 MB)
    int*            flags = (int*)d_ws;                               // 16 KB
    unsigned short* hring = (unsigned short*)(flags + NWGR * 8 * FSTRIDE); // 192 KB
    _Float16*       W16   = (_Float16*)(hring + 3 * BHID);            // 4 MB
    _Float16*       U16   = W16 + (size_t)G2 * HID;                   // 4 MB
    _Float16*       xact  = U16 + (size_t)G2 * HID;                   // 32 MB
    _Float16*       wbuf  = xact + (size_t)BATCH * TLEN * HID;        // 64 MB

    dim3 gg(16384 / 128, 2048 / 128);
    int init_blocks = (BHID + 255) / 256;

    // ---- layer 0 ----
    conv_f16<<<(BATCH * TLEN * 512 / 8 + 255) / 256, 256, 0, stream>>>(
        x, xact, BATCH * TLEN * 512 / 8);
    conv_f16<<<(G2 * 512 / 8 + 255) / 256, 256, 0, stream>>>(
        W0, W16, G2 * 512 / 8);
    conv_f16<<<(G2 * HID / 8 + 255) / 256, 256, 0, stream>>>(
        U0, U16, G2 * HID / 8);
    proj_gemm_f16<<<gg, 256, 0, stream>>>(xact, W16, wbuf, 512);
    rec_init<<<init_blocks, 256, 0, stream>>>(hring, flags);
    ligru_rec<<<dim3(NWGR), dim3(512), 0, stream>>>(
        wbuf, U16, hring, flags, nullptr, xact, hstack);  // fp16 act out

    // ---- layer 1 ----
    conv_f16<<<(G2 * HID / 8 + 255) / 256, 256, 0, stream>>>(
        W1, W16, G2 * HID / 8);
    conv_f16<<<(G2 * HID / 8 + 255) / 256, 256, 0, stream>>>(
        U1, U16, G2 * HID / 8);
    proj_gemm_f16<<<gg, 256, 0, stream>>>(xact, W16, wbuf, 1024);
    rec_init<<<init_blocks, 256, 0, stream>>>(hring, flags);
    ligru_rec<<<dim3(NWGR), dim3(512), 0, stream>>>(
        wbuf, U16, hring, flags, out, nullptr, hstack + BHID);
}

// Round 14
// 7653.465 us; speedup vs baseline: 1.6888x; 1.6888x over previous
//
#include <hip/hip_runtime.h>
#include <math.h>

#define BATCH 32
#define TLEN  512
#define HID   1024
#define G2    2048   // 2*H
#define BHID (BATCH * HID)

typedef _Float16 half8 __attribute__((ext_vector_type(8)));
typedef float f32x4 __attribute__((ext_vector_type(4)));

// ---------------------------------------------------------------------------
// fp32 -> fp16 conversion (8 elems/thread)
// ---------------------------------------------------------------------------
__global__ __launch_bounds__(256)
void conv_f16(const float* __restrict__ s, _Float16* __restrict__ d, int n8) {
    int i = blockIdx.x * 256 + threadIdx.x;
    if (i < n8) {
        int base = i * 8;
        float4 v0 = *(const float4*)&s[base];
        float4 v1 = *(const float4*)&s[base + 4];
        half8 h;
        h[0] = (_Float16)v0.x; h[1] = (_Float16)v0.y;
        h[2] = (_Float16)v0.z; h[3] = (_Float16)v0.w;
        h[4] = (_Float16)v1.x; h[5] = (_Float16)v1.y;
        h[6] = (_Float16)v1.z; h[7] = (_Float16)v1.w;
        *(half8*)&d[base] = h;
    }
}

// ---------------------------------------------------------------------------
// MFMA projection GEMM (proven R11-R13): Cw[t][b][n] = sum_k A[m][k]*W[n][k],
// m = b*T + t. fp16 in, fp16 out.
// ---------------------------------------------------------------------------
__global__ __launch_bounds__(256)
void proj_gemm_f16(const _Float16* __restrict__ A, const _Float16* __restrict__ W,
                   _Float16* __restrict__ Cw, int K) {
    const int tid = threadIdx.x;
    const int wv = tid >> 6;
    const int l  = tid & 63;
    const int m0 = blockIdx.x * 128 + (wv >> 1) * 64;
    const int n0 = blockIdx.y * 128 + (wv & 1) * 64;
    const int fr = l & 15;
    const int kg = l >> 4;

    f32x4 acc[4][4];
    #pragma unroll
    for (int i = 0; i < 4; ++i)
        #pragma unroll
        for (int j = 0; j < 4; ++j) acc[i][j] = (f32x4){0.f, 0.f, 0.f, 0.f};

    const int nkc = K >> 5;
    #pragma unroll 2
    for (int kc = 0; kc < nkc; ++kc) {
        int k = kc * 32 + kg * 8;
        half8 af[4], bf[4];
        #pragma unroll
        for (int i = 0; i < 4; ++i)
            af[i] = *(const half8*)&A[(size_t)(m0 + i * 16 + fr) * K + k];
        #pragma unroll
        for (int j = 0; j < 4; ++j)
            bf[j] = *(const half8*)&W[(size_t)(n0 + j * 16 + fr) * K + k];
        #pragma unroll
        for (int i = 0; i < 4; ++i)
            #pragma unroll
            for (int j = 0; j < 4; ++j)
                acc[i][j] = __builtin_amdgcn_mfma_f32_16x16x32_f16(
                    af[i], bf[j], acc[i][j], 0, 0, 0);
    }

    #pragma unroll
    for (int i = 0; i < 4; ++i) {
        #pragma unroll
        for (int r = 0; r < 4; ++r) {
            int m = m0 + i * 16 + (l >> 4) * 4 + r;
            int t = m & (TLEN - 1);
            int b = m >> 9;
            _Float16* dst = &Cw[((size_t)t * BATCH + b) * G2];
            #pragma unroll
            for (int j = 0; j < 4; ++j)
                dst[n0 + j * 16 + (l & 15)] = (_Float16)acc[i][j][r];
        }
    }
}

// ---------------------------------------------------------------------------
// Agent-scope (device-coherent) helpers: sc0 sc1, bypass L1/per-XCD L2.
// ---------------------------------------------------------------------------
__device__ __forceinline__ unsigned int ld_tag(const unsigned int* p) {
    return __hip_atomic_load(p, __ATOMIC_RELAXED, __HIP_MEMORY_SCOPE_AGENT);
}
__device__ __forceinline__ void st_tag64(unsigned long long* p, unsigned long long v) {
    __hip_atomic_store(p, v, __ATOMIC_RELAXED, __HIP_MEMORY_SCOPE_AGENT);
}

#define NWG 256
#define BT 8         // batches per WG
#define JT 16        // a-rows per WG (plus JT z-rows)

// tagged h ring: u32 = (epoch << 16) | fp16(h).  tag of h(t) = t+1.
__global__ void rec_init(unsigned int* ring) {
    int i = blockIdx.x * 256 + threadIdx.x;
    if (i < 3 * BHID) ring[i] = (i < BHID) ? (1u << 16) : 0u;
}

// ---------------------------------------------------------------------------
// MFMA recurrence, single-LLC-hop sync (tag-in-word).
// R10 skeleton: 256 WGs x 512 thr (8 waves), bt = wg&3 (4 sync groups),
// jb = wg>>2, WG owns 16 j-rows (a+z) x 8 batches. Wave wv = K-chunks
// wv*4..wv*4+3. A frags from preconverted U16 (32 VGPR). C partials reduced
// via LDS red[t&1] (double-buffered), ONE __syncthreads per step.
//
// h exchange: ring[3][B][H] of tagged u32. Publish = plain coherent store of
// (tag|fp16) -- self-describing, no vmcnt, no flag. Consume = bulk-issue all
// 32 B-words, then per-kc tag-check with retry. One LLC round trip replaces
// R10's store->drain->flag->poll->load (3 trips).
// Safety: 3-ring + monotone tags (WAR-free by the R6 induction); red[2]
// double-buffer makes wave skew safe (wave at t+2 implies own gates done t).
// ---------------------------------------------------------------------------
__global__ __launch_bounds__(512, 1)
void ligru_rec(const _Float16* __restrict__ w16,   // [T][B][2H] fp16
               const _Float16* __restrict__ U16,   // [2H][H] fp16
               unsigned int* __restrict__ ring,    // [3][B][H] tagged
               float* __restrict__ out32,          // [B][T][H] fp32 (layer 1)
               _Float16* __restrict__ act16,       // [B][T][H] fp16 (layer 0)
               float* __restrict__ hlast) {        // [B][H] fp32
    __shared__ float red[2][8][32][17];            // double-buffered partials

    const int wg  = blockIdx.x;
    const int tid = threadIdx.x;
    const int bt  = wg & 3;
    const int jb  = wg >> 2;          // 0..63
    const int j0  = jb * JT;
    const int bg0 = bt * BT;

    const int wv   = tid >> 6;        // wave 0..7: K-chunks wv*4..wv*4+3
    const int l    = tid & 63;
    const int mrow = l & 15;          // A-frag M row
    const int kg   = l >> 4;          // k-group (8 halves)
    const int bcol = bg0 + (l & 7);   // B-frag batch (cols 8-15 duplicate)

    // ---- A frags from preconverted fp16 U (8 frags = 32 VGPR)
    half8 Aa[4], Az[4];
    #pragma unroll
    for (int kc = 0; kc < 4; ++kc) {
        int k0 = (wv * 4 + kc) * 32 + kg * 8;
        Aa[kc] = *(const half8*)&U16[(size_t)(j0 + mrow) * HID + k0];
        Az[kc] = *(const half8*)&U16[(size_t)(HID + j0 + mrow) * HID + k0];
    }

    unsigned int* r_t = ring;
    unsigned int* r_n = ring + BHID;
    unsigned int* r_p = ring + 2 * BHID;

    // gate coords (tid < 128): jl = row 0..15, bl = batch 0..7
    const int jl = tid & 15;
    const int bl = tid >> 4;
    const int bg = bg0 + bl;
    float hprev = 0.f;

    for (int t = 0; t < TLEN; ++t) {
        // ---- w prefetch (gate threads; issued before the B-poll)
        float wa = 0.f, wz = 0.f;
        if (tid < 128) {
            const _Float16* wt = &w16[((size_t)t * BATCH + bg) * G2];
            wa = (float)wt[j0 + jl];
            wz = (float)wt[HID + j0 + jl];
        }

        // ---- bulk-issue all 32 tagged B words, then per-kc check+retry+MFMA
        const unsigned int* hb = r_t + (size_t)bcol * HID + wv * 128 + kg * 8;
        unsigned int v[32];
        #pragma unroll
        for (int kc = 0; kc < 4; ++kc)
            #pragma unroll
            for (int i = 0; i < 8; ++i)
                v[kc * 8 + i] = ld_tag(hb + kc * 32 + i);

        const unsigned int want = (unsigned int)(t + 1);
        f32x4 ca = {0.f, 0.f, 0.f, 0.f};
        f32x4 cz = {0.f, 0.f, 0.f, 0.f};
        #pragma unroll
        for (int kc = 0; kc < 4; ++kc) {
            bool ok = true;
            #pragma unroll
            for (int i = 0; i < 8; ++i)
                ok &= (v[kc * 8 + i] >> 16) == want;
            while (!ok) {
                __builtin_amdgcn_s_sleep(1);
                ok = true;
                #pragma unroll
                for (int i = 0; i < 8; ++i) {
                    v[kc * 8 + i] = ld_tag(hb + kc * 32 + i);
                    ok &= (v[kc * 8 + i] >> 16) == want;
                }
            }
            union { unsigned short s[8]; half8 h; } B;
            #pragma unroll
            for (int i = 0; i < 8; ++i)
                B.s[i] = (unsigned short)v[kc * 8 + i];
            ca = __builtin_amdgcn_mfma_f32_16x16x32_f16(Aa[kc], B.h, ca, 0, 0, 0);
            cz = __builtin_amdgcn_mfma_f32_16x16x32_f16(Az[kc], B.h, cz, 0, 0, 0);
        }

        // ---- C layout: col = l&15 (batch), row = (l>>4)*4 + r (j)
        #pragma unroll
        for (int r = 0; r < 4; ++r) {
            red[t & 1][wv][kg * 4 + r][l & 15]      = ca[r];
            red[t & 1][wv][16 + kg * 4 + r][l & 15] = cz[r];
        }
        __syncthreads();   // the only block barrier per step

        // ---- gates + state update + tagged publish (128 threads)
        if (tid < 128) {
            float sa = 0.f, sz = 0.f;
            #pragma unroll
            for (int p = 0; p < 8; ++p) {
                sa += red[t & 1][p][jl][bl];
                sz += red[t & 1][p][16 + jl][bl];
            }
            float at = wa + sa;
            float zt = wz + sz;
            zt = 1.f / (1.f + expf(-zt));
            float hc = tanhf(at);
            float hnew = zt * hprev + (1.f - zt) * hc;
            hprev = hnew;

            unsigned short h16 =
                __builtin_bit_cast(unsigned short, (_Float16)hnew);
            // outputs
            if (act16) {
                unsigned int other = __shfl_xor((unsigned int)h16, 1);
                if ((jl & 1) == 0) {
                    unsigned int pk = (unsigned int)h16 | (other << 16);
                    *(unsigned int*)&act16[((size_t)bg * TLEN + t) * HID
                                           + j0 + jl] = pk;
                }
            } else {
                out32[((size_t)bg * TLEN + t) * HID + j0 + jl] = hnew;
            }
            // publish h(t+1): tagged words, no fence, no flag
            if (t < TLEN - 1) {
                unsigned int tagged =
                    ((unsigned int)(t + 2) << 16) | (unsigned int)h16;
                unsigned int other = __shfl_xor(tagged, 1);
                if ((jl & 1) == 0) {
                    unsigned long long pk =
                        (unsigned long long)tagged |
                        ((unsigned long long)other << 32);
                    st_tag64((unsigned long long*)&r_n[(size_t)bg * HID
                                                       + j0 + jl], pk);
                }
            } else {
                hlast[(size_t)bg * HID + j0 + jl] = hnew;
            }
        }

        unsigned int* tmp = r_t; r_t = r_n; r_n = r_p; r_p = tmp;
    }
}

// ---------------------------------------------------------------------------
extern "C" void kernel_launch(void* const* d_in, const int* in_sizes, int n_in,
                              void* d_out, int out_size, void* d_ws, size_t ws_size,
                              hipStream_t stream) {
    (void)in_sizes; (void)n_in; (void)out_size; (void)ws_size;

    const float* x  = (const float*)d_in[0];
    const float* W0 = (const float*)d_in[1];
    const float* U0 = (const float*)d_in[2];
    const float* W1 = (const float*)d_in[3];
    const float* U1 = (const float*)d_in[4];

    float* out    = (float*)d_out;                              // [B,T,H]
    float* hstack = out + (size_t)BATCH * TLEN * HID;           // [2,B,H]

    // workspace layout
    unsigned int* ring = (unsigned int*)d_ws;                         // 384 KB
    _Float16*     W16  = (_Float16*)(ring + 3 * BHID);                // 4 MB
    _Float16*     U16  = W16 + (size_t)G2 * HID;                      // 4 MB
    _Float16*     xact = U16 + (size_t)G2 * HID;                      // 32 MB
    _Float16*     wbuf = xact + (size_t)BATCH * TLEN * HID;           // 64 MB

    dim3 gg(16384 / 128, 2048 / 128);
    int ring_blocks = (3 * BHID + 255) / 256;

    // ---- layer 0 ----
    conv_f16<<<(BATCH * TLEN * 512 / 8 + 255) / 256, 256, 0, stream>>>(
        x, xact, BATCH * TLEN * 512 / 8);
    conv_f16<<<(G2 * 512 / 8 + 255) / 256, 256, 0, stream>>>(
        W0, W16, G2 * 512 / 8);
    conv_f16<<<(G2 * HID / 8 + 255) / 256, 256, 0, stream>>>(
        U0, U16, G2 * HID / 8);
    proj_gemm_f16<<<gg, 256, 0, stream>>>(xact, W16, wbuf, 512);
    rec_init<<<ring_blocks, 256, 0, stream>>>(ring);
    ligru_rec<<<dim3(NWG), dim3(512), 0, stream>>>(
        wbuf, U16, ring, nullptr, xact, hstack);   // fp16 act out

    // ---- layer 1 ----
    conv_f16<<<(G2 * HID / 8 + 255) / 256, 256, 0, stream>>>(
        W1, W16, G2 * HID / 8);
    conv_f16<<<(G2 * HID / 8 + 255) / 256, 256, 0, stream>>>(
        U1, U16, G2 * HID / 8);
    proj_gemm_f16<<<gg, 256, 0, stream>>>(xact, W16, wbuf, 1024);
    rec_init<<<ring_blocks, 256, 0, stream>>>(ring);
    ligru_rec<<<dim3(NWG), dim3(512), 0, stream>>>(
        wbuf, U16, ring, out, nullptr, hstack + BHID);
}

// Round 15
// 3925.888 us; speedup vs baseline: 3.2922x; 1.9495x over previous
//
#include <hip/hip_runtime.h>
#include <math.h>

#define BATCH 32
#define TLEN  512
#define HID   1024
#define G2    2048   // 2*H
#define BHID (BATCH * HID)

typedef _Float16 half8 __attribute__((ext_vector_type(8)));
typedef float f32x4 __attribute__((ext_vector_type(4)));

// ---------------------------------------------------------------------------
// fp32 -> fp16 conversion (8 elems/thread)
// ---------------------------------------------------------------------------
__global__ __launch_bounds__(256)
void conv_f16(const float* __restrict__ s, _Float16* __restrict__ d, int n8) {
    int i = blockIdx.x * 256 + threadIdx.x;
    if (i < n8) {
        int base = i * 8;
        float4 v0 = *(const float4*)&s[base];
        float4 v1 = *(const float4*)&s[base + 4];
        half8 h;
        h[0] = (_Float16)v0.x; h[1] = (_Float16)v0.y;
        h[2] = (_Float16)v0.z; h[3] = (_Float16)v0.w;
        h[4] = (_Float16)v1.x; h[5] = (_Float16)v1.y;
        h[6] = (_Float16)v1.z; h[7] = (_Float16)v1.w;
        *(half8*)&d[base] = h;
    }
}

// ---------------------------------------------------------------------------
// MFMA projection GEMM (proven R11-R14): Cw[t][b][n] = sum_k A[m][k]*W[n][k],
// m = b*T + t. fp16 in, fp16 out.
// ---------------------------------------------------------------------------
__global__ __launch_bounds__(256)
void proj_gemm_f16(const _Float16* __restrict__ A, const _Float16* __restrict__ W,
                   _Float16* __restrict__ Cw, int K) {
    const int tid = threadIdx.x;
    const int wv = tid >> 6;
    const int l  = tid & 63;
    const int m0 = blockIdx.x * 128 + (wv >> 1) * 64;
    const int n0 = blockIdx.y * 128 + (wv & 1) * 64;
    const int fr = l & 15;
    const int kg = l >> 4;

    f32x4 acc[4][4];
    #pragma unroll
    for (int i = 0; i < 4; ++i)
        #pragma unroll
        for (int j = 0; j < 4; ++j) acc[i][j] = (f32x4){0.f, 0.f, 0.f, 0.f};

    const int nkc = K >> 5;
    #pragma unroll 2
    for (int kc = 0; kc < nkc; ++kc) {
        int k = kc * 32 + kg * 8;
        half8 af[4], bf[4];
        #pragma unroll
        for (int i = 0; i < 4; ++i)
            af[i] = *(const half8*)&A[(size_t)(m0 + i * 16 + fr) * K + k];
        #pragma unroll
        for (int j = 0; j < 4; ++j)
            bf[j] = *(const half8*)&W[(size_t)(n0 + j * 16 + fr) * K + k];
        #pragma unroll
        for (int i = 0; i < 4; ++i)
            #pragma unroll
            for (int j = 0; j < 4; ++j)
                acc[i][j] = __builtin_amdgcn_mfma_f32_16x16x32_f16(
                    af[i], bf[j], acc[i][j], 0, 0, 0);
    }

    #pragma unroll
    for (int i = 0; i < 4; ++i) {
        #pragma unroll
        for (int r = 0; r < 4; ++r) {
            int m = m0 + i * 16 + (l >> 4) * 4 + r;
            int t = m & (TLEN - 1);
            int b = m >> 9;
            _Float16* dst = &Cw[((size_t)t * BATCH + b) * G2];
            #pragma unroll
            for (int j = 0; j < 4; ++j)
                dst[n0 + j * 16 + (l & 15)] = (_Float16)acc[i][j][r];
        }
    }
}

// ---------------------------------------------------------------------------
// Agent-scope (device-coherent) helpers: sc0 sc1, bypass L1/per-XCD L2.
// ---------------------------------------------------------------------------
__device__ __forceinline__ void st_flag(int* p, int v) {
    __hip_atomic_store(p, v, __ATOMIC_RELAXED, __HIP_MEMORY_SCOPE_AGENT);
}
__device__ __forceinline__ int ld_flag(const int* p) {
    return __hip_atomic_load(p, __ATOMIC_RELAXED, __HIP_MEMORY_SCOPE_AGENT);
}
__device__ __forceinline__ unsigned long long ld_h2u(const unsigned short* p) {
    return __hip_atomic_load((const unsigned long long*)p, __ATOMIC_RELAXED,
                             __HIP_MEMORY_SCOPE_AGENT);
}
__device__ __forceinline__ void st_h32(unsigned int* p, unsigned int v) {
    __hip_atomic_store(p, v, __ATOMIC_RELAXED, __HIP_MEMORY_SCOPE_AGENT);
}

#define NWG 256
#define FSTRIDE 16   // flags 64 B apart
#define BT 8         // batches per WG
#define JT 16        // a-rows per WG (plus JT z-rows)

__global__ void rec_init(unsigned short* h0, int* flags) {
    int i = blockIdx.x * 256 + threadIdx.x;
    if (i < BHID) h0[i] = 0;              // fp16 +0.0
    if (i < NWG * FSTRIDE) flags[i] = 0;
}

// ---------------------------------------------------------------------------
// MFMA recurrence -- R10's verified 1.81 ms kernel, unchanged structure:
// 256 WGs x 512 thr (8 waves); bt = wg&3 (4 sync groups x 64 WGs); WG owns
// 16 j-rows (a+z) x 8 batches; wave wv = K-chunks wv*4..wv*4+3; A-frags in
// registers (32 VGPR); B-frags = coherent 8B loads from the fp16 3-ring;
// C partials through red[8][32][17] LDS; gates on tid<128; 3 barriers/step;
// publish = packed coherent h-store + drain + per-WG flag; poll = 64 flags,
// one per lane of the first 64 threads.
// R15 deltas ONLY: (1) w read as fp16, (2) A-frags load from preconverted
// U16, (3) h-store issued before the out/act store.
// ---------------------------------------------------------------------------
__global__ __launch_bounds__(512, 1)
void ligru_rec(const _Float16* __restrict__ w16,   // [T][B][2H] fp16
               const _Float16* __restrict__ U16,   // [2H][H] fp16
               unsigned short* __restrict__ hring, // [3][B][H] fp16 ring
               int* __restrict__ flags,            // NWG*FSTRIDE, pre-zeroed
               float* __restrict__ out32,          // [B][T][H] fp32 (layer 1)
               _Float16* __restrict__ act16,       // [B][T][H] fp16 (layer 0)
               float* __restrict__ hlast) {        // [B][H] fp32
    __shared__ float red[8][32][17];               // wave C partials (17 KB)

    const int wg  = blockIdx.x;
    const int tid = threadIdx.x;
    const int bt  = wg & 3;
    const int jb  = wg >> 2;          // 0..63
    const int j0  = jb * JT;
    const int bg0 = bt * BT;

    const int wv   = tid >> 6;        // wave 0..7: K-chunks wv*4..wv*4+3
    const int l    = tid & 63;
    const int mrow = l & 15;          // A-frag M row
    const int kg   = l >> 4;          // k-group (8 halves)
    const int bcol = bg0 + (l & 7);   // B-frag batch (cols 8-15 duplicate)

    // ---- A frags from preconverted fp16 U (8 frags = 32 VGPR)
    half8 Aa[4], Az[4];
    #pragma unroll
    for (int kc = 0; kc < 4; ++kc) {
        int k0 = (wv * 4 + kc) * 32 + kg * 8;
        Aa[kc] = *(const half8*)&U16[(size_t)(j0 + mrow) * HID + k0];
        Az[kc] = *(const half8*)&U16[(size_t)(HID + j0 + mrow) * HID + k0];
    }

    unsigned short* h_t = hring;
    unsigned short* h_n = hring + BHID;
    unsigned short* h_p = hring + 2 * BHID;

    // gate coords (tid < 128): jl = row 0..15, bl = batch 0..7
    const int jl = tid & 15;
    const int bl = tid >> 4;
    const int bg = bg0 + bl;
    float hprev = 0.f;

    for (int t = 0; t < TLEN; ++t) {
        // ---- w prefetch (fp16, gate threads; issued before the poll)
        float wa = 0.f, wz = 0.f;
        if (tid < 128) {
            const _Float16* wt = &w16[((size_t)t * BATCH + bg) * G2];
            wa = (float)wt[j0 + jl];
            wz = (float)wt[HID + j0 + jl];
        }

        // ---- wait for the 64 group peers to have published h(t)
        if (t > 0) {
            if (tid < 64) {
                const int* fp = &flags[((tid << 2) + bt) * FSTRIDE];
                while (ld_flag(fp) < t)
                    __builtin_amdgcn_s_sleep(1);
            }
            __syncthreads();   // barrier A
        }

        // ---- B frags from coherent ring + MFMA (8 per wave)
        f32x4 ca = {0.f, 0.f, 0.f, 0.f};
        f32x4 cz = {0.f, 0.f, 0.f, 0.f};
        #pragma unroll
        for (int kc = 0; kc < 4; ++kc) {
            int k0 = (wv * 4 + kc) * 32 + kg * 8;
            const unsigned short* hp = &h_t[(size_t)bcol * HID + k0];
            union { unsigned long long u[2]; half8 h; } B;
            B.u[0] = ld_h2u(hp);
            B.u[1] = ld_h2u(hp + 4);
            ca = __builtin_amdgcn_mfma_f32_16x16x32_f16(Aa[kc], B.h, ca, 0, 0, 0);
            cz = __builtin_amdgcn_mfma_f32_16x16x32_f16(Az[kc], B.h, cz, 0, 0, 0);
        }

        // ---- C layout: col = l&15 (batch), row = (l>>4)*4 + r (j)
        #pragma unroll
        for (int r = 0; r < 4; ++r) {
            red[wv][kg * 4 + r][l & 15]      = ca[r];
            red[wv][16 + kg * 4 + r][l & 15] = cz[r];
        }
        __syncthreads();   // barrier B: partials complete

        // ---- gates + state update (128 threads)
        if (tid < 128) {
            float sa = 0.f, sz = 0.f;
            #pragma unroll
            for (int v = 0; v < 8; ++v) {
                sa += red[v][jl][bl];
                sz += red[v][16 + jl][bl];
            }
            float at = wa + sa;
            float zt = wz + sz;
            zt = 1.f / (1.f + expf(-zt));
            float hc = tanhf(at);
            float hnew = zt * hprev + (1.f - zt) * hc;
            hprev = hnew;

            unsigned short h16 =
                __builtin_bit_cast(unsigned short, (_Float16)hnew);
            unsigned int other = __shfl_xor((unsigned int)h16, 1);
            unsigned int pk = ((jl & 1) == 0)
                ? ((unsigned int)h16 | (other << 16))
                : ((other) | ((unsigned int)h16 << 16));

            // h publish FIRST (leads the drain queue)
            if (t < TLEN - 1) {
                if ((jl & 1) == 0)
                    st_h32((unsigned int*)&h_n[(size_t)bg * HID + j0 + jl], pk);
            } else {
                hlast[(size_t)bg * HID + j0 + jl] = hnew;
            }
            // then the layer output
            if (act16) {
                if ((jl & 1) == 0)
                    *(unsigned int*)&act16[((size_t)bg * TLEN + t) * HID
                                           + j0 + jl] = pk;
            } else {
                out32[((size_t)bg * TLEN + t) * HID + j0 + jl] = hnew;
            }
        }

        // ---- publish barrier + flag
        if (t < TLEN - 1) {
            __syncthreads();   // barrier C: drains vmcnt -> h stores at LLC
            if (tid == 0) st_flag(&flags[wg * FSTRIDE], t + 1);
        }

        unsigned short* tmp = h_t; h_t = h_n; h_n = h_p; h_p = tmp;
    }
}

// ---------------------------------------------------------------------------
extern "C" void kernel_launch(void* const* d_in, const int* in_sizes, int n_in,
                              void* d_out, int out_size, void* d_ws, size_t ws_size,
                              hipStream_t stream) {
    (void)in_sizes; (void)n_in; (void)out_size; (void)ws_size;

    const float* x  = (const float*)d_in[0];
    const float* W0 = (const float*)d_in[1];
    const float* U0 = (const float*)d_in[2];
    const float* W1 = (const float*)d_in[3];
    const float* U1 = (const float*)d_in[4];

    float* out    = (float*)d_out;                              // [B,T,H]
    float* hstack = out + (size_t)BATCH * TLEN * HID;           // [2,B,H]

    // workspace layout
    int*            flags = (int*)d_ws;                               // 16 KB
    unsigned short* hring = (unsigned short*)(flags + NWG * FSTRIDE); // 192 KB
    _Float16*       W16   = (_Float16*)(hring + 3 * BHID);            // 4 MB
    _Float16*       U16   = W16 + (size_t)G2 * HID;                   // 4 MB
    _Float16*       xact  = U16 + (size_t)G2 * HID;                   // 32 MB
    _Float16*       wbuf  = xact + (size_t)BATCH * TLEN * HID;        // 64 MB

    dim3 gg(16384 / 128, 2048 / 128);
    int init_blocks = (BHID + 255) / 256;

    // ---- layer 0 ----
    conv_f16<<<(BATCH * TLEN * 512 / 8 + 255) / 256, 256, 0, stream>>>(
        x, xact, BATCH * TLEN * 512 / 8);
    conv_f16<<<(G2 * 512 / 8 + 255) / 256, 256, 0, stream>>>(
        W0, W16, G2 * 512 / 8);
    conv_f16<<<(G2 * HID / 8 + 255) / 256, 256, 0, stream>>>(
        U0, U16, G2 * HID / 8);
    proj_gemm_f16<<<gg, 256, 0, stream>>>(xact, W16, wbuf, 512);
    rec_init<<<init_blocks, 256, 0, stream>>>(hring, flags);
    ligru_rec<<<dim3(NWG), dim3(512), 0, stream>>>(
        wbuf, U16, hring, flags, nullptr, xact, hstack);  // fp16 act out

    // ---- layer 1 ----
    conv_f16<<<(G2 * HID / 8 + 255) / 256, 256, 0, stream>>>(
        W1, W16, G2 * HID / 8);
    conv_f16<<<(G2 * HID / 8 + 255) / 256, 256, 0, stream>>>(
        U1, U16, G2 * HID / 8);
    proj_gemm_f16<<<gg, 256, 0, stream>>>(xact, W16, wbuf, 1024);
    rec_init<<<init_blocks, 256, 0, stream>>>(hring, flags);
    ligru_rec<<<dim3(NWG), dim3(512), 0, stream>>>(
        wbuf, U16, hring, flags, out, nullptr, hstack + BHID);
}